// Round 1
// 2419.825 us; speedup vs baseline: 2.0521x; 2.0521x over previous
//
#include <hip/hip_runtime.h>

// GRU B=64 S=512 I=512 H=1024 — fp32 in/out, bf16 MFMA compute.
// Persistent weight-stationary kernel: 256 WGs (1/CU) = 4 batch-groups x 64 CUs;
// each CU owns 16 batches x 16 dims, weights live in VGPRs (bf16).
//
// v2: sync rework (the old version spent ~9.7us/step in a 64-way counter
// barrier + full agent fences):
//  - per-(block,wave) flag stores instead of serialized fetch_add barrier
//  - consumers: each WAVE polls only its 16 producer blocks (64 flags, one
//    coalesced lane-per-flag atomic load + __all ballot)
//  - fence-free: all exchanged data (h, flags) moves via agent-scope atomics
//    (coherent at MALL); producer orders h-stores -> flag with a hand-rolled
//    s_waitcnt vmcnt(0) (what LLVM emits for atomic release ordering anyway,
//    minus the buffer_wbl2 L2 flush we don't need)
//  - single __syncthreads per step (LDS reduce buffer double-buffered)
//  - x-projection loads prefetched 1 step ahead into registers; x MFMAs +
//    bf16 converts run BEFORE the poll (independent of h) to fill the wait
//  - out[] stores nontemporal + issued after the flag (off critical path)
// ws: [0,256KB) h ping-pong bf16; +4KB flags (zeroed per launch).

#define B_ 64
#define S_ 512
#define I_ 512
#define H_ 1024

typedef short short8 __attribute__((ext_vector_type(8)));
typedef float f32x4 __attribute__((ext_vector_type(4)));
typedef unsigned long long u64x2 __attribute__((ext_vector_type(2)));

__device__ __forceinline__ unsigned short f2bf(float f) {
    unsigned u = __builtin_bit_cast(unsigned, f);
    u += 0x7fffu + ((u >> 16) & 1u);
    return (unsigned short)(u >> 16);
}
__device__ __forceinline__ float sigm(float x) { return 1.f / (1.f + __expf(-x)); }
__device__ __forceinline__ float tanh_(float x) { return 2.f / (1.f + __expf(-2.f * x)) - 1.f; }

__device__ __forceinline__ f32x4 MFMA(short8 a, short8 b, f32x4 c) {
    return __builtin_amdgcn_mfma_f32_16x16x32_bf16(a, b, c, 0, 0, 0);
}

__device__ __forceinline__ short8 cvt8(float4 a, float4 b) {
    short8 r;
    r[0] = (short)f2bf(a.x); r[1] = (short)f2bf(a.y); r[2] = (short)f2bf(a.z); r[3] = (short)f2bf(a.w);
    r[4] = (short)f2bf(b.x); r[5] = (short)f2bf(b.y); r[6] = (short)f2bf(b.z); r[7] = (short)f2bf(b.w);
    return r;
}
__device__ __forceinline__ short8 load8bf(const float* p) {
    return cvt8(*(const float4*)p, *(const float4*)(p + 4));
}

__launch_bounds__(256, 1)
__global__ void gru_persistent(const float* __restrict__ xin,            // [B,S,I] fp32
                               unsigned short* hbase,                    // ws ping-pong bf16
                               unsigned* flags,                          // [4][64][4] u32
                               const float* __restrict__ w_ih,           // [3H,I] fp32
                               const float* __restrict__ w_hh,           // [3H,H] fp32
                               const float* __restrict__ b_ihp,          // [3H] fp32
                               const float* __restrict__ b_hhp,          // [3H] fp32
                               const float* __restrict__ h0,             // [B,H] fp32
                               float* __restrict__ out) {                // fp32 [B,S,H]+[B,H]
    const int tid = threadIdx.x;
    const int w = tid >> 6;        // wave id: K-slice owner
    const int l = tid & 63;
    const int ln = l & 15;         // A-frag: batch row / B-frag: dim col
    const int lq = l >> 4;         // quad -> k sub-offset
    const int grp = blockIdx.x & 3;      // batch group (16 batches)
    const int cu  = blockIdx.x >> 2;     // dim slice  (16 dims)
    const int b0 = grp * 16, d0 = cu * 16;

    // ---- startup: weight B-fragments fp32 -> bf16 -> VGPRs ----
    short8 Whr[8], Whz[8], Whn[8], Wir[4], Wiz[4], Win[4];
    {
        const int nrow = d0 + ln;
        #pragma unroll
        for (int f = 0; f < 8; ++f) {
            int k = w * 256 + f * 32 + lq * 8;
            Whr[f] = load8bf(w_hh + (size_t)(0 * H_ + nrow) * H_ + k);
            Whz[f] = load8bf(w_hh + (size_t)(1 * H_ + nrow) * H_ + k);
            Whn[f] = load8bf(w_hh + (size_t)(2 * H_ + nrow) * H_ + k);
        }
        #pragma unroll
        for (int f = 0; f < 4; ++f) {
            int k = w * 128 + f * 32 + lq * 8;
            Wir[f] = load8bf(w_ih + (size_t)(0 * H_ + nrow) * I_ + k);
            Wiz[f] = load8bf(w_ih + (size_t)(1 * H_ + nrow) * I_ + k);
            Win[f] = load8bf(w_ih + (size_t)(2 * H_ + nrow) * I_ + k);
        }
    }

    // ---- per-thread elementwise assignment: (m_t = batch, n_t = dim) ----
    const int n_t = tid & 15, m_t = tid >> 4;
    const int d = d0 + n_t;
    const float b_r  = b_ihp[d]          + b_hhp[d];
    const float b_z  = b_ihp[H_ + d]     + b_hhp[H_ + d];
    const float b_in = b_ihp[2 * H_ + d];
    const float b_hn = b_hhp[2 * H_ + d];
    float hprev = h0[(size_t)(b0 + m_t) * H_ + d];   // fp32 state in register

    // double-buffered reduction scratch: [parity][gate][wave][n16][m pad20]
    __shared__ float red[2 * 4 * 4 * 16 * 20];

    const int ha_base = (b0 + ln) * H_ + w * 256 + lq * 8;        // + f*32 (shorts)
    const float* xrow = xin + (size_t)(b0 + ln) * S_ * I_ + w * 128 + lq * 8;

    // flags layout: [grp][cu][wave] u32. Producer (grp,cu,w) sets cu*4+w = t+1.
    // Consumer wave w needs producers cu' in [16w,16w+16), all 4 waves
    //   -> indices [64w, 64w+64): lane l polls exactly one flag (coalesced).
    unsigned* const myflag = flags + grp * 256 + cu * 4 + w;
    unsigned* const pollp  = flags + grp * 256 + w * 64 + l;

    // x prefetch registers (one step ahead)
    float4 xf[8];
    #pragma unroll
    for (int f = 0; f < 4; ++f) {
        xf[2 * f]     = *(const float4*)(xrow + f * 32);
        xf[2 * f + 1] = *(const float4*)(xrow + f * 32 + 4);
    }

    for (int t = 0; t < S_; ++t) {
        // ---- x-gate work first: independent of h, fills the wait window ----
        short8 xA[4];
        #pragma unroll
        for (int f = 0; f < 4; ++f) xA[f] = cvt8(xf[2 * f], xf[2 * f + 1]);

        f32x4 ar = {0,0,0,0}, az = {0,0,0,0}, anh = {0,0,0,0}, anx = {0,0,0,0};
        #pragma unroll
        for (int f = 0; f < 4; ++f) {
            ar  = MFMA(xA[f], Wir[f], ar);
            az  = MFMA(xA[f], Wiz[f], az);
            anx = MFMA(xA[f], Win[f], anx);
        }

        // ---- wait for this wave's 16 producer blocks, then pull h ----
        short8 hA[8];
        if (t == 0) {
            #pragma unroll
            for (int f = 0; f < 8; ++f)
                hA[f] = load8bf(h0 + (size_t)(b0 + ln) * H_ + w * 256 + f * 32 + lq * 8);
        } else {
            int guard = 0;
            for (;;) {
                unsigned fv = __hip_atomic_load(pollp, __ATOMIC_RELAXED, __HIP_MEMORY_SCOPE_AGENT);
                if (__all((int)(fv >= (unsigned)t))) break;
                if ((++guard & 255) == 0) __builtin_amdgcn_s_sleep(1);
                if (guard > (1 << 20)) break;   // safety valve vs infinite hang
            }
            asm volatile("" ::: "memory");      // no hoisting of the h loads above the poll
            const unsigned short* hc = hbase + (size_t)(t & 1) * (B_ * H_);
            #pragma unroll
            for (int f = 0; f < 8; ++f) {
                unsigned long long* p = (unsigned long long*)(hc + ha_base + f * 32);
                u64x2 v;
                v[0] = __hip_atomic_load(p,     __ATOMIC_RELAXED, __HIP_MEMORY_SCOPE_AGENT);
                v[1] = __hip_atomic_load(p + 1, __ATOMIC_RELAXED, __HIP_MEMORY_SCOPE_AGENT);
                hA[f] = __builtin_bit_cast(short8, v);
            }
        }

        #pragma unroll
        for (int f = 0; f < 8; ++f) {
            ar  = MFMA(hA[f], Whr[f], ar);
            az  = MFMA(hA[f], Whz[f], az);
            anh = MFMA(hA[f], Whn[f], anh);
        }

        // partials -> LDS (double-buffered). D layout: col(n)=lane&15, row(m)=quad*4+reg
        const int pb = (t & 1) ? 5120 : 0;
        {
            int rbase = pb + (w * 16 + ln) * 20 + lq * 4;
            *(f32x4*)&red[rbase]        = ar;
            *(f32x4*)&red[rbase + 1280] = az;
            *(f32x4*)&red[rbase + 2560] = anh;
            *(f32x4*)&red[rbase + 3840] = anx;
        }
        __syncthreads();   // the ONLY barrier per step

        float rp = 0.f, zp = 0.f, nhp = 0.f, nxp = 0.f;
        #pragma unroll
        for (int ww = 0; ww < 4; ++ww) {
            int ib = pb + (ww * 16 + n_t) * 20 + m_t;
            rp  += red[ib];
            zp  += red[ib + 1280];
            nhp += red[ib + 2560];
            nxp += red[ib + 3840];
        }
        float r = sigm(rp + b_r);
        float z = sigm(zp + b_z);
        float nn = tanh_(nxp + b_in + r * (nhp + b_hn));
        float h = nn + z * (hprev - nn);   // (1-z)*n + z*h
        hprev = h;

        // ---- publish h + per-wave flag (critical path) ----
        if (t < S_ - 1) {
            unsigned short* hnx = hbase + (size_t)((t + 1) & 1) * (B_ * H_);
            unsigned hb16 = f2bf(h);
            unsigned ob = (unsigned)__shfl_xor((int)hb16, 1, 64);
            if ((tid & 1) == 0) {
                unsigned packed = (hb16 & 0xffffu) | (ob << 16);
                __hip_atomic_store((unsigned*)(hnx + (size_t)(b0 + m_t) * H_ + d),
                                   packed, __ATOMIC_RELAXED, __HIP_MEMORY_SCOPE_AGENT);
            }
            // order: h-store acks (coherent point) before flag store issues.
            asm volatile("s_waitcnt vmcnt(0)" ::: "memory");
            if (l == 0)
                __hip_atomic_store(myflag, (unsigned)(t + 1),
                                   __ATOMIC_RELAXED, __HIP_MEMORY_SCOPE_AGENT);
        }

        // ---- off critical path: output store + next-step x prefetch ----
        __builtin_nontemporal_store(h, &out[((size_t)(b0 + m_t) * S_ + t) * H_ + d]);
        if (t == S_ - 1)
            out[(size_t)B_ * S_ * H_ + (size_t)(b0 + m_t) * H_ + d] = h;

        if (t < S_ - 1) {
            const float* xp = xrow + (size_t)(t + 1) * I_;
            #pragma unroll
            for (int f = 0; f < 4; ++f) {
                xf[2 * f]     = *(const float4*)(xp + f * 32);
                xf[2 * f + 1] = *(const float4*)(xp + f * 32 + 4);
            }
        }
    }
}

extern "C" void kernel_launch(void* const* d_in, const int* in_sizes, int n_in,
                              void* d_out, int out_size, void* d_ws, size_t ws_size,
                              hipStream_t stream) {
    const float* xin  = (const float*)d_in[0];   // fp32 [B,S,I]
    const float* h0   = (const float*)d_in[1];   // fp32 [1,B,H]
    const float* w_ih = (const float*)d_in[2];   // fp32 [3H,I]
    const float* w_hh = (const float*)d_in[3];   // fp32 [3H,H]
    const float* b_ih = (const float*)d_in[4];   // fp32 [3H]
    const float* b_hh = (const float*)d_in[5];   // fp32 [3H]
    // size-based disambiguation (w_ih: 3H*I elems, w_hh: 3H*H)
    if (n_in >= 4 && in_sizes[2] == 3 * H_ * H_ && in_sizes[3] == 3 * H_ * I_) {
        const float* tmp = w_ih; w_ih = w_hh; w_hh = tmp;
    }
    float* out = (float*)d_out;                  // fp32 outputs + hn

    unsigned short* hb = (unsigned short*)d_ws;                   // 2 x B*H bf16
    unsigned* flags = (unsigned*)(hb + 2 * (size_t)B_ * H_);      // [4][64][4] u32

    // flags must be zeroed every launch (ws is re-poisoned to 0xAA)
    hipMemsetAsync(flags, 0, 4096, stream);

    hipLaunchKernelGGL(gru_persistent, dim3(256), dim3(256), 0, stream,
                       xin, hb, flags, w_ih, w_hh, b_ih, b_hh, h0, out);
}